// Round 6
// baseline (86.281 us; speedup 1.0000x reference)
//
#include <hip/hip_runtime.h>

#define DMD 128
#define NV 64
#define BB 2
#define SQ 512
#define NBN 128                 // BB*NV
#define ASCALE 0.08838834764831845f   // 128^-0.5
#define L2E 1.4426950408889634f
#define CSC (ASCALE * L2E)

// workspace layout (float offsets)
#define WS_XE  0                       // [NBN][DMD]
#define WS_PW  (WS_XE + NBN*DMD)       // [BB][2]
#define WS_VEC (WS_PW + 4)             // 9*128
#define WS_OB  (WS_VEC + 9*DMD)        // [NBN][DMD][DMD] branch-0 output
// branch-1 output lives in d_out (read then overwritten by k_out)

// ---------------- xe[bn][t] = sum_s x[b,s,n]*W_emb[s,t] + b_emb[t] ----------------
__global__ __launch_bounds__(512) void k_xe(const float* __restrict__ x,
                                            const float* __restrict__ W_emb,
                                            const float* __restrict__ b_emb,
                                            float* __restrict__ ws) {
    int bn = blockIdx.x;
    int b = bn >> 6, n = bn & 63;
    int tid = threadIdx.x;
    int t = tid & 127, sc = tid >> 7;
    __shared__ float xsh[SQ];
    __shared__ float part[3][DMD];
    xsh[tid] = x[(b * SQ + tid) * NV + n];
    __syncthreads();
    float acc = 0.f;
    const float* W = W_emb + (sc * 128) * DMD + t;
#pragma unroll 8
    for (int s = 0; s < 128; ++s) acc = fmaf(xsh[sc * 128 + s], W[s * DMD], acc);
    if (sc) part[sc - 1][t] = acc;
    __syncthreads();
    if (sc == 0)
        ws[WS_XE + bn * DMD + t] = acc + part[0][t] + part[1][t] + part[2][t] + b_emb[t];
}

// ---------------- merged: period weights (blocks 0,1) + rank-1 vectors (block 2) ----------------
__global__ __launch_bounds__(128) void k_prep(const int* __restrict__ f1p,
                                              const int* __restrict__ f2p,
                                              const float* __restrict__ Wel, const float* __restrict__ bel,
                                              const float* __restrict__ W_start, const float* __restrict__ b_start,
                                              const float* __restrict__ Wq, const float* __restrict__ bq,
                                              const float* __restrict__ Wk, const float* __restrict__ bk,
                                              const float* __restrict__ Wv, const float* __restrict__ bv,
                                              float* __restrict__ ws) {
    int tid = threadIdx.x;
    __shared__ float ct[DMD], st[DMD];
    __shared__ float a2[2];
    __shared__ float A[DMD], C[DMD], BL[DMD];
    if (blockIdx.x < 2) {
        int b = blockIdx.x;
        float ang = (float)tid * 0.04908738521234052f;   // 2*pi/128
        ct[tid] = cosf(ang);
        st[tid] = sinf(ang);
        __syncthreads();
        int k = tid >> 6;
        int n = tid & 63;
        int f = k ? f2p[0] : f1p[0];
        const float* xr = ws + WS_XE + (b * NV + n) * DMD;
        float re = 0.f, im = 0.f;
#pragma unroll 8
        for (int t = 0; t < DMD; ++t) {
            int ph = (f * t) & (DMD - 1);
            float v = xr[t];
            re = fmaf(v, ct[ph], re);
            im = fmaf(v, st[ph], im);
        }
        float amp = sqrtf(re * re + im * im);
        for (int off = 32; off > 0; off >>= 1) amp += __shfl_down(amp, off);
        if (n == 0) a2[k] = amp * (1.0f / NV);
        __syncthreads();
        if (tid == 0) {
            float m = fmaxf(a2[0], a2[1]);
            float e0 = expf(a2[0] - m), e1 = expf(a2[1] - m);
            float inv = 1.0f / (e0 + e1);
            ws[WS_PW + b * 2 + 0] = e0 * inv;
            ws[WS_PW + b * 2 + 1] = e1 * inv;
        }
    } else {
        int e = tid;
        float a = 0.f, c = 0.f;
        for (int d = 0; d < DMD; ++d) {
            float w = Wel[e * DMD + d];
            a = fmaf(w, W_start[d], a);
            c = fmaf(w, b_start[d], c);
        }
        A[e] = a;
        C[e] = c + bel[e];
        BL[e] = bel[e];
        __syncthreads();
        float aq = 0, cq = 0, pq = 0, ak = 0, ck = 0, pk = 0, av = 0, cv = 0, pv = 0;
        for (int d = 0; d < DMD; ++d) {
            float Ad = A[d], Cd = C[d], Bd = BL[d];
            float wq = Wq[e * DMD + d], wk = Wk[e * DMD + d], wv = Wv[e * DMD + d];
            aq = fmaf(wq, Ad, aq); cq = fmaf(wq, Cd, cq); pq = fmaf(wq, Bd, pq);
            ak = fmaf(wk, Ad, ak); ck = fmaf(wk, Cd, ck); pk = fmaf(wk, Bd, pk);
            av = fmaf(wv, Ad, av); cv = fmaf(wv, Cd, cv); pv = fmaf(wv, Bd, pv);
        }
        float* V = ws + WS_VEC;
        V[0 * DMD + e] = aq; V[1 * DMD + e] = cq + bq[e]; V[2 * DMD + e] = pq + bq[e];
        V[3 * DMD + e] = ak; V[4 * DMD + e] = ck + bk[e]; V[5 * DMD + e] = pk + bk[e];
        V[6 * DMD + e] = av; V[7 * DMD + e] = cv + bv[e]; V[8 * DMD + e] = pv + bv[e];
    }
}

// ============ attention paths (single branch per block, direct global stores) ============

// Rank-1: P == 128 (f == 1)
__device__ __forceinline__ void attn_rank1(float pwv, const float (*Vsh)[4],
                                           const float* xs, float* __restrict__ ob,
                                           int rowbase, int tid) {
    float xi = xs[tid];
    float t[4], l[4], ax[4];
#pragma unroll
    for (int k = 0; k < 4; ++k) {
        float Aq = Vsh[0][k], Cq = Vsh[1][k], Ak = Vsh[3][k];
        t[k] = CSC * fmaf(xi, Aq, Cq) * Ak;
        l[k] = 0.f; ax[k] = 0.f;
    }
#pragma unroll 4
    for (int j = 0; j < DMD; ++j) {
        float xj = xs[j];
#pragma unroll
        for (int k = 0; k < 4; ++k) {
            float ev = exp2f(t[k] * xj);
            l[k] += ev;
            ax[k] = fmaf(ev, xj, ax[k]);
        }
    }
#pragma unroll
    for (int k = 0; k < 4; ++k) {
        float Av = Vsh[6][k], Cv = Vsh[7][k];
        float o = fmaf(Av, ax[k] / l[k], Cv);
        ob[rowbase + k * DMD + tid] = pwv * o;
    }
}

// pow2-P path: P in {32,64}, no padding; EB e's batched per pass for exp ILP
template<int PP, int NP, int EB>
__device__ __forceinline__ void attn_pow2(float pwv, const float (*Vsh)[4],
                                          const float* xs, float* __restrict__ ob,
                                          int rowbase, int tid) {
    const int UH = PP / 4;
    int lane4 = tid & 3, i0 = tid >> 2, jb = lane4 * UH;

    float xq[NP][UH], U2[UH];
#pragma unroll
    for (int u = 0; u < UH; ++u) {
        int j = jb + u;
        float s = 0.f;
#pragma unroll
        for (int q = 0; q < NP; ++q) { float xv = xs[q * PP + j]; xq[q][u] = xv; s += xv; }
        U2[u] = s;
    }
    const int NREP = (PP == 64) ? 2 : 1;
#pragma unroll
    for (int rep = 0; rep < NREP; ++rep) {
        int i = i0 + rep * 32;
        float G2[UH];
#pragma unroll
        for (int u = 0; u < UH; ++u) G2[u] = 0.f;
#pragma unroll
        for (int q = 0; q < NP; ++q) {
            float xi = xs[q * PP + i];
#pragma unroll
            for (int u = 0; u < UH; ++u) G2[u] = fmaf(xi, xq[q][u], G2[u]);
        }
#pragma unroll
        for (int eg = 0; eg < 4; eg += EB) {
            float d1[EB], d2[EB], l[EB];
            float accq[NP][EB];
#pragma unroll
            for (int k = 0; k < EB; ++k) {
                float t = CSC * Vsh[3][eg + k];
                d1[k] = t * Vsh[0][eg + k];
                d2[k] = t * Vsh[1][eg + k];
                l[k] = 0.f;
#pragma unroll
                for (int q = 0; q < NP; ++q) accq[q][k] = 0.f;
            }
#pragma unroll
            for (int u = 0; u < UH; ++u) {
                float gg = G2[u], uu = U2[u];
                float ev[EB];
#pragma unroll
                for (int k = 0; k < EB; ++k) ev[k] = exp2f(fmaf(d1[k], gg, d2[k] * uu));
#pragma unroll
                for (int k = 0; k < EB; ++k) {
                    l[k] += ev[k];
#pragma unroll
                    for (int q = 0; q < NP; ++q) accq[q][k] = fmaf(ev[k], xq[q][u], accq[q][k]);
                }
            }
#pragma unroll
            for (int k = 0; k < EB; ++k) { l[k] += __shfl_xor(l[k], 1); l[k] += __shfl_xor(l[k], 2); }
#pragma unroll
            for (int q = 0; q < NP; ++q)
#pragma unroll
                for (int k = 0; k < EB; ++k) {
                    accq[q][k] += __shfl_xor(accq[q][k], 1);
                    accq[q][k] += __shfl_xor(accq[q][k], 2);
                }
            if (lane4 == 0) {
#pragma unroll
                for (int k = 0; k < EB; ++k) {
                    float li = 1.f / l[k];
                    float Av = Vsh[6][eg + k], Cv = Vsh[7][eg + k];
#pragma unroll
                    for (int q = 0; q < NP; ++q) {
                        float o = fmaf(Av, accq[q][k] * li, Cv);
                        ob[rowbase + (eg + k) * DMD + i * NP + q] = pwv * o;
                    }
                }
            }
        }
    }
}

// small-P path: P <= 16. Scores for all 4 e's computed once (2 slots/thread) -> LDS W,
// single barrier, PV thread-per-output, direct stores.
template<int UB>
__device__ __forceinline__ void attn_small(
    int P, int pn, int r, int Prows, float pwv,
    const float (*Vsh)[4], const float* xs, const float* U, const float* xt,
    float* W, float* __restrict__ ob, int rowbase, int tid)
{
    int GP = P + 1;
    int tot = Prows * P;
    unsigned mP = (4096u + (unsigned)P - 1u) / (unsigned)P;     // ceil(4096/P)
    unsigned mpn = (4096u + (unsigned)pn - 1u) / (unsigned)pn;  // ceil(4096/pn)

    // ---- slot 0 (score idx = tid) ----
    bool v0 = (tid < tot);
    int i0 = (int)(((unsigned)tid * mP) >> 12);
    int j0 = tid - i0 * P;
    bool A0 = (i0 < r), c0 = (j0 < r);
    float xtj0 = xt[j0], Uj0 = U[j0];
    float xti0 = A0 ? xt[i0] : 0.f;
    float g0 = 0.f;
    for (int p = 0; p < pn - 1; ++p) g0 = fmaf(xs[p * P + i0], xs[p * P + j0], g0);
    float Gx0 = (A0 && c0) ? fmaf(xti0, xtj0, g0) : g0;
    float Ux0 = (A0 && c0) ? Uj0 + xtj0 : Uj0;
    float Xw0 = (!A0 && c0) ? xtj0 : 0.f;
    float mw0 = c0 ? 1.f : 0.f;
    int wa0 = i0 * GP + j0;

    // ---- slot 1 (score idx = tid + 128) ----
    int idx1 = tid + 128;
    bool v1 = (idx1 < tot);
    int idx1c = v1 ? idx1 : 0;
    int i1 = (int)(((unsigned)idx1c * mP) >> 12);
    int j1 = idx1c - i1 * P;
    bool A1 = (i1 < r), c1 = (j1 < r);
    float xtj1 = xt[j1], Uj1 = U[j1];
    float xti1 = A1 ? xt[i1] : 0.f;
    float g1 = 0.f;
    for (int p = 0; p < pn - 1; ++p) g1 = fmaf(xs[p * P + i1], xs[p * P + j1], g1);
    float Gx1 = (A1 && c1) ? fmaf(xti1, xtj1, g1) : g1;
    float Ux1 = (A1 && c1) ? Uj1 + xtj1 : Uj1;
    float Xw1 = (!A1 && c1) ? xtj1 : 0.f;
    float mw1 = c1 ? 1.f : 0.f;
    int wa1 = i1 * GP + j1;

    // ---- PV assignment: output mo = tid -> (i2, p2) ----
    int i2 = (int)(((unsigned)tid * mpn) >> 12);
    int p2 = tid - i2 * pn;
    bool lastp = (p2 == pn - 1);
    int row2 = i2 * GP;
    float xsr[UB];
#pragma unroll
    for (int j = 0; j < UB; ++j) {
        int idx = p2 * P + j;
        xsr[j] = (j < P && idx < DMD) ? xs[idx] : 0.f;
    }

    // ---- score phase: 8 exps batched, one barrier ----
    float s[4][2];
#pragma unroll
    for (int ec = 0; ec < 4; ++ec) {
        float Aq = Vsh[0][ec], Cq = Vsh[1][ec], Pq = Vsh[2][ec];
        float Ak = Vsh[3][ec], Ck = Vsh[4][ec], Pk = Vsh[5][ec];
        float t = CSC * Ak;
        float d1 = t * Aq, d2 = t * Cq, d3 = t * Pq;
        float ckpk = CSC * (Ck - Pk);
        float aS0 = A0 ? fmaf(Aq, xti0, Cq) : Pq;
        s[ec][0] = fmaf(d1, Gx0, fmaf(d2, Ux0, fmaf(d3, Xw0, (ckpk * aS0) * mw0)));
        float aS1 = A1 ? fmaf(Aq, xti1, Cq) : Pq;
        s[ec][1] = fmaf(d1, Gx1, fmaf(d2, Ux1, fmaf(d3, Xw1, (ckpk * aS1) * mw1)));
    }
#pragma unroll
    for (int ec = 0; ec < 4; ++ec) { s[ec][0] = exp2f(s[ec][0]); s[ec][1] = exp2f(s[ec][1]); }
#pragma unroll
    for (int ec = 0; ec < 4; ++ec) {
        if (v0) W[ec * 288 + wa0] = s[ec][0];
        if (v1) W[ec * 288 + wa1] = s[ec][1];
    }
    __syncthreads();

    // ---- PV phase ----
#pragma unroll
    for (int ec = 0; ec < 4; ++ec) {
        float Av = Vsh[6][ec], Cv = Vsh[7][ec], Pv = Vsh[8][ec];
        float l = 0.f, wr = 0.f, ax = 0.f;
#pragma unroll
        for (int j = 0; j < UB; ++j) {
            float w = W[ec * 288 + row2 + ((j < P) ? j : 0)];
            w = (j < P) ? w : 0.f;
            l += w;
            wr += (j < r) ? w : 0.f;
            ax = fmaf(w, xsr[j], ax);
        }
        float li = 1.f / l;
        float o;
        if (lastp) { float sl = wr * li; o = fmaf(Av, ax * li, fmaf(Cv, sl, Pv * (1.f - sl))); }
        else       o = fmaf(Av, ax * li, Cv);
        ob[rowbase + ec * DMD + tid] = pwv * o;
    }
}

// mid-P path (P in {18,21,25,42}): register scheme with masks, direct stores
template<int UH, int NP>
__device__ __forceinline__ void attn_midA(
    int P, int pn, int r, int Prows, float pwv,
    const float (*Vsh)[4], const float* xs, const float* U,
    const float* xt, float* __restrict__ ob, int rowbase, int tid)
{
    int lane4 = tid & 3;
    int i0 = tid >> 2;
    int jb = lane4 * UH;

    float Ur[UH], xtr[UH], xq0[UH], xq1[UH];
#pragma unroll
    for (int u = 0; u < UH; ++u) {
        int j = jb + u, jc = (j < P) ? j : 0;
        Ur[u] = U[jc];
        xtr[u] = xt[jc];
        xq0[u] = (j < DMD) ? xs[j] : 0.f;
        int i1x = P + j;
        xq1[u] = (i1x < DMD) ? xs[i1x] : 0.f;
    }
    int nrep = (Prows > 32) ? 2 : 1;
    for (int rep = 0; rep < nrep; ++rep) {
        int i = i0 + rep * 32;
        bool rowact = (i < Prows);
        int ic = rowact ? i : 0;
        float xtic = xt[ic];
        bool rowvalid = (ic < r);
        float g[UH];
#pragma unroll
        for (int u = 0; u < UH; ++u) g[u] = 0.f;
        for (int p = 0; p < pn - 1; ++p) {
            float xi = xs[p * P + ic];
#pragma unroll
            for (int u = 0; u < UH; ++u) {
                int j = jb + u, jc = (j < P) ? j : 0;
                g[u] = fmaf(xi, xs[p * P + jc], g[u]);
            }
        }
        for (int ec = 0; ec < 4; ++ec) {
            float Aq = Vsh[0][ec], Cq = Vsh[1][ec], Pq = Vsh[2][ec];
            float Ak = Vsh[3][ec], Ck = Vsh[4][ec], Pk = Vsh[5][ec];
            float Av = Vsh[6][ec], Cv = Vsh[7][ec], Pv = Vsh[8][ec];
            float c1 = CSC * Aq * Ak, c3 = CSC * Cq * Ak;
            float asi = CSC * (rowvalid ? fmaf(xtic, Aq, Cq) : Pq);

            float l0 = 0.f, l1 = 0.f, w0 = 0.f, w1 = 0.f;
            float accq[NP];
#pragma unroll
            for (int q = 0; q < NP; ++q) accq[q] = 0.f;
#pragma unroll
            for (int u = 0; u < UH; ++u) {
                int j = jb + u;
                float bK = (j < r) ? fmaf(xtr[u], Ak, Ck) : Pk;
                float S = fmaf(asi, bK, fmaf(c3, Ur[u], c1 * g[u]));
                float ev = exp2f(S);
                ev = (j < P) ? ev : 0.f;
                if (u & 1) l1 += ev; else l0 += ev;
                float evr = (j < r) ? ev : 0.f;
                if (u & 1) w1 += evr; else w0 += evr;
                accq[0] = fmaf(ev, xq0[u], accq[0]);
                if (NP >= 2) accq[1] = fmaf(ev, xq1[u], accq[1]);
#pragma unroll
                for (int q = 2; q < NP; ++q) {
                    int idx = q * P + j;
                    float xv = (idx < DMD) ? xs[idx] : 0.f;
                    accq[q] = fmaf(ev, xv, accq[q]);
                }
            }
            float l = l0 + l1, wr = w0 + w1;
            l += __shfl_xor(l, 1);  l += __shfl_xor(l, 2);
            wr += __shfl_xor(wr, 1); wr += __shfl_xor(wr, 2);
#pragma unroll
            for (int q = 0; q < NP; ++q) {
                if (q < pn) {
                    accq[q] += __shfl_xor(accq[q], 1);
                    accq[q] += __shfl_xor(accq[q], 2);
                }
            }
            if (lane4 == 0 && rowact) {
                float li = 1.f / l;
#pragma unroll
                for (int q = 0; q < NP; ++q) {
                    if (q < pn) {
                        int mo = i * pn + q;
                        if (mo < DMD) {
                            float o;
                            if (q == pn - 1) {
                                float sl = wr * li;
                                o = fmaf(Av, accq[q] * li, fmaf(Cv, sl, Pv * (1.f - sl)));
                            } else {
                                o = fmaf(Av, accq[q] * li, Cv);
                            }
                            ob[rowbase + ec * DMD + mo] = pwv * o;
                        }
                    }
                }
            }
        }
    }
}

__global__ __launch_bounds__(128) void k_attn(const int* __restrict__ f1p,
                                              const int* __restrict__ f2p,
                                              float* __restrict__ ws,
                                              float* __restrict__ outb) {
    int bn = blockIdx.y, b = bn >> 6;
    int e0 = blockIdx.x * 4;           // 32 chunks of 4 e's
    int br = blockIdx.z;               // branch split across grid
    int tid = threadIdx.x;

    __shared__ float xs[DMD], U[64], xt[64];
    __shared__ float Vsh[9][4];
    __shared__ float W[4 * 288];

    xs[tid] = ws[WS_XE + bn * DMD + tid];
    if (tid < 36) Vsh[tid >> 2][tid & 3] = ws[WS_VEC + (tid >> 2) * DMD + e0 + (tid & 3)];
    int f = br ? f2p[0] : f1p[0];
    float pwv = ws[WS_PW + b * 2 + br];
    float* ob = br ? outb : (ws + WS_OB);
    int rowbase = (bn * DMD + e0) * DMD;
    __syncthreads();

    int P = DMD / f;
    int pn = (DMD + P - 1) / P;
    int r = DMD - (pn - 1) * P;
    int Prows = (DMD + pn - 1) / pn;

    if (P == DMD) {
        attn_rank1(pwv, Vsh, xs, ob, rowbase, tid);
        return;
    }
    if (tid < P) {
        float s = 0.f;
        for (int p = 0; p < pn - 1; ++p) s += xs[p * P + tid];
        U[tid] = s;
        xt[tid] = (tid < r) ? xs[(pn - 1) * P + tid] : 0.f;
    }
    __syncthreads();

    if (P <= 4)       attn_small<4>(P, pn, r, Prows, pwv, Vsh, xs, U, xt, W, ob, rowbase, tid);
    else if (P <= 8)  attn_small<8>(P, pn, r, Prows, pwv, Vsh, xs, U, xt, W, ob, rowbase, tid);
    else if (P <= 16) attn_small<16>(P, pn, r, Prows, pwv, Vsh, xs, U, xt, W, ob, rowbase, tid);
    else if (P == 64) attn_pow2<64, 2, 2>(pwv, Vsh, xs, ob, rowbase, tid);
    else if (P == 32) attn_pow2<32, 4, 4>(pwv, Vsh, xs, ob, rowbase, tid);
    else if (P > 32)  attn_midA<16, 4>(P, pn, r, Prows, pwv, Vsh, xs, U, xt, ob, rowbase, tid);  // P=42
    else              attn_midA<8, 8>(P, pn, r, Prows, pwv, Vsh, xs, U, xt, ob, rowbase, tid);   // 18,21,25
}

// ---------------- out[bn][e][h] = sum_m (ob0+ob1)[bn][e][m]*Wo[h][m] + bo[h] ----------------
// ob1 lives in `out` itself; each block reads only its own rows (all reads complete
// before any write thanks to the post-load __syncthreads in the last chunk).
__global__ __launch_bounds__(256) void k_out(const float* __restrict__ Wo,
                                             const float* __restrict__ bo,
                                             const float* __restrict__ ws,
                                             float* __restrict__ out) {
    int blk = blockIdx.x;          // 256 = 64 bn-pairs * 4 e-quarters
    int bn0 = (blk >> 2) * 2;
    int e0  = (blk & 3) * 32;
    int tid = threadIdx.x;
    __shared__ __align__(16) float WTc[32 * 132];    // [mm][h]
    __shared__ __align__(16) float oT[2][32][36];    // [bnl][mm][e]
    int hg = tid & 31, eg = tid >> 5, h0 = hg * 4;

    float acc[2][4][4];
#pragma unroll
    for (int a = 0; a < 2; ++a)
#pragma unroll
        for (int c = 0; c < 4; ++c)
#pragma unroll
            for (int d = 0; d < 4; ++d) acc[a][c][d] = 0.f;

    for (int mc = 0; mc < 4; ++mc) {
        int m0 = mc * 32;
        __syncthreads();
        for (int idx = tid; idx < 4096; idx += 256) {
            int h = idx >> 5, mm = idx & 31;
            WTc[mm * 132 + h] = Wo[h * DMD + m0 + mm];
        }
        for (int idx = tid; idx < 2048; idx += 256) {
            int bnl = idx >> 10, rem = idx & 1023, e = rem >> 5, mm = rem & 31;
            int gi = ((bn0 + bnl) * DMD + e0 + e) * DMD + m0 + mm;
            oT[bnl][mm][e] = ws[WS_OB + gi] + out[gi];
        }
        __syncthreads();
#pragma unroll 4
        for (int mm = 0; mm < 32; ++mm) {
            const float4 wv = *reinterpret_cast<const float4*>(&WTc[mm * 132 + h0]);
            const float4 q0 = *reinterpret_cast<const float4*>(&oT[0][mm][eg * 4]);
            const float4 q1 = *reinterpret_cast<const float4*>(&oT[1][mm][eg * 4]);
            float ae[2][4] = {{q0.x, q0.y, q0.z, q0.w}, {q1.x, q1.y, q1.z, q1.w}};
#pragma unroll
            for (int bnl = 0; bnl < 2; ++bnl) {
#pragma unroll
                for (int el = 0; el < 4; ++el) {
                    float a = ae[bnl][el];
                    acc[bnl][el][0] = fmaf(a, wv.x, acc[bnl][el][0]);
                    acc[bnl][el][1] = fmaf(a, wv.y, acc[bnl][el][1]);
                    acc[bnl][el][2] = fmaf(a, wv.z, acc[bnl][el][2]);
                    acc[bnl][el][3] = fmaf(a, wv.w, acc[bnl][el][3]);
                }
            }
        }
    }
    const float4 bov = *reinterpret_cast<const float4*>(&bo[h0]);
#pragma unroll
    for (int bnl = 0; bnl < 2; ++bnl) {
#pragma unroll
        for (int el = 0; el < 4; ++el) {
            float4 res = { acc[bnl][el][0] + bov.x, acc[bnl][el][1] + bov.y,
                           acc[bnl][el][2] + bov.z, acc[bnl][el][3] + bov.w };
            int e = e0 + eg * 4 + el;
            *reinterpret_cast<float4*>(&out[((bn0 + bnl) * DMD + e) * DMD + h0]) = res;
        }
    }
}

extern "C" void kernel_launch(void* const* d_in, const int* in_sizes, int n_in,
                              void* d_out, int out_size, void* d_ws, size_t ws_size,
                              hipStream_t stream) {
    const float* x       = (const float*)d_in[0];
    const float* W_emb   = (const float*)d_in[1];
    const float* b_emb   = (const float*)d_in[2];
    const float* W_start = (const float*)d_in[3];
    const float* b_start = (const float*)d_in[4];
    const float* Wel     = (const float*)d_in[5];
    const float* bel     = (const float*)d_in[6];
    const float* Wq      = (const float*)d_in[7];
    const float* bq      = (const float*)d_in[8];
    const float* Wk      = (const float*)d_in[9];
    const float* bk      = (const float*)d_in[10];
    const float* Wv      = (const float*)d_in[11];
    const float* bv      = (const float*)d_in[12];
    const float* Wo      = (const float*)d_in[13];
    const float* bo      = (const float*)d_in[14];
    const int*   f1p     = (const int*)d_in[15];
    const int*   f2p     = (const int*)d_in[16];
    float* ws  = (float*)d_ws;
    float* out = (float*)d_out;

    k_xe<<<NBN, 512, 0, stream>>>(x, W_emb, b_emb, ws);
    k_prep<<<3, 128, 0, stream>>>(f1p, f2p, Wel, bel, W_start, b_start,
                                  Wq, bq, Wk, bk, Wv, bv, ws);
    k_attn<<<dim3(32, NBN, 2), 128, 0, stream>>>(f1p, f2p, ws, out);
    k_out<<<256, 256, 0, stream>>>(Wo, bo, ws, out);
}